// Round 1
// baseline (16651.108 us; speedup 1.0000x reference)
//
#include <hip/hip_runtime.h>
#include <math.h>

#define NB    2048
#define NE    32       // N_ELEC
#define NN    8        // N_NUC
#define EMB   256
#define TPS   32
#define E_SAME 480
#define E_ANTI 512
#define E_NE   256

#define SF_STRIDE 356  // 352 + 4 pad (breaks %32 bank aliasing for scatter atomics)
#define HX_STRIDE 33   // 32 + 1 pad (conflict-free per-sender gather)

__launch_bounds__(256, 2)
__global__ void gnn_kernel(
    const float* __restrict__ elec, const float* __restrict__ nuc,
    const float* __restrict__ fs,  const float* __restrict__ fa,  const float* __restrict__ fn,
    const float* __restrict__ u_w1, const float* __restrict__ u_b1,
    const float* __restrict__ u_w2, const float* __restrict__ u_b2,
    const float* __restrict__ w_w1, const float* __restrict__ w_b1,
    const float* __restrict__ w_w2, const float* __restrict__ w_b2,
    const float* __restrict__ h_w1, const float* __restrict__ h_b1,
    const float* __restrict__ h_w2, const float* __restrict__ h_b2,
    const float* __restrict__ g_w1, const float* __restrict__ g_b1,
    const float* __restrict__ g_w2, const float* __restrict__ g_b2,
    const int* __restrict__ ss, const int* __restrict__ rs,
    const int* __restrict__ sa, const int* __restrict__ ra,
    const int* __restrict__ sn, const int* __restrict__ rn,
    float* __restrict__ out)
{
    __shared__ float s_f[NE * SF_STRIDE];   // 45568 B : f = [elec(256) | z_ne | z_same | z_anti]
    __shared__ float s_b[16 * 256];         // 16384 B : hx[72][33] (phases A-C), hidden[16][256] (phase E)

    const int tid = threadIdx.x;
    const int b   = blockIdx.x;

    // ---------------- Phase A: hx = mlp(sender_nodes, h[t]) for 72 (node,type) rows ----------------
    // 72 nodes * 32 cols = 2304 items = 9 * 256. t is wave-uniform per iteration.
    #pragma unroll
    for (int i = 0; i < 9; ++i) {
        int item = tid + i * 256;
        int n = item >> 5, j = item & 31;
        int t = n >> 5;                               // 0,1: electrons ; 2: nuclei
        const float* x = (t < 2) ? (elec + ((size_t)b * NE + (n & 31)) * EMB)
                                 : (nuc  + ((size_t)b * NN + (n - 64)) * EMB);
        const float* w = h_w1 + (size_t)t * EMB * TPS + j;
        float a = h_b1[t * TPS + j];
        for (int k = 0; k < EMB; k += 4) {
            float4 xv = *reinterpret_cast<const float4*>(x + k);
            a += xv.x * w[(k + 0) * TPS] + xv.y * w[(k + 1) * TPS]
               + xv.z * w[(k + 2) * TPS] + xv.w * w[(k + 3) * TPS];
        }
        s_f[item] = tanhf(a);                          // layer-1 tmp lives in s_f (free until Phase B)
    }
    __syncthreads();
    #pragma unroll
    for (int i = 0; i < 9; ++i) {
        int item = tid + i * 256;
        int n = item >> 5, j = item & 31;
        int t = n >> 5;
        const float* w   = h_w2 + t * TPS * TPS + j;
        const float* tmp = s_f + n * TPS;
        float a = h_b2[t * TPS + j];
        #pragma unroll
        for (int k = 0; k < TPS; ++k) a += tmp[k] * w[k * TPS];
        s_b[n * HX_STRIDE + j] = a;                    // hx
    }
    __syncthreads();

    // ---------------- Phase B: f[:, :256] = electrons ; f[:, 256:352] = 0 ----------------
    for (int r = 0; r < NE; ++r)
        s_f[r * SF_STRIDE + tid] = elec[((size_t)b * NE + r) * EMB + tid];
    #pragma unroll
    for (int i = 0; i < 12; ++i) {                    // 32*96 = 3072 = 12*256
        int idx = tid + i * 256;
        int r = idx / 96, c = idx - r * 96;
        s_f[r * SF_STRIDE + 256 + c] = 0.f;
    }
    __syncthreads();

    // ---------------- Phase C: edge MLPs + scatter ----------------
    for (int t = 0; t < 3; ++t) {
        const float* ft; const int* snd; const int* rcv; int cnt, zoff;
        if (t == 0)      { ft = fs; snd = ss; rcv = rs; cnt = E_SAME; zoff = 288; }
        else if (t == 1) { ft = fa; snd = sa; rcv = ra; cnt = E_ANTI; zoff = 320; }
        else             { ft = fn; snd = sn; rcv = rn; cnt = E_NE;   zoff = 256; }
        const float* uw1 = u_w1 + t * TPS * TPS; const float* ub1 = u_b1 + t * TPS;
        const float* uw2 = u_w2 + t * TPS * TPS; const float* ub2 = u_b2 + t * TPS;
        const float* ww1 = w_w1 + t * TPS * TPS; const float* wb1 = w_b1 + t * TPS;
        const float* ww2 = w_w2 + t * TPS * TPS; const float* wb2 = w_b2 + t * TPS;
        const float* hxb = s_b + t * 32 * HX_STRIDE;

        for (int e = tid; e < cnt; e += 256) {
            float fr[TPS];
            const float4* fp = reinterpret_cast<const float4*>(ft + ((size_t)b * cnt + e) * TPS);
            #pragma unroll
            for (int i = 0; i < 8; ++i) {
                float4 v = fp[i];
                fr[4*i] = v.x; fr[4*i+1] = v.y; fr[4*i+2] = v.z; fr[4*i+3] = v.w;
            }
            // u-MLP layer 1
            float h1[TPS];
            #pragma unroll
            for (int j = 0; j < TPS; ++j) {
                float a = ub1[j];
                #pragma unroll
                for (int k = 0; k < TPS; ++k) a += fr[k] * uw1[k * TPS + j];
                h1[j] = tanhf(a);
            }
            // u-MLP layer 2 + residual -> e
            float ev[TPS];
            #pragma unroll
            for (int j = 0; j < TPS; ++j) {
                float a = ub2[j];
                #pragma unroll
                for (int k = 0; k < TPS; ++k) a += h1[k] * uw2[k * TPS + j];
                ev[j] = fr[j] + a;
            }
            // w-MLP layer 1
            #pragma unroll
            for (int j = 0; j < TPS; ++j) {
                float a = wb1[j];
                #pragma unroll
                for (int k = 0; k < TPS; ++k) a += ev[k] * ww1[k * TPS + j];
                h1[j] = tanhf(a);
            }
            // w-MLP layer 2, msg = we * hx[sender], scatter-add to receiver
            int sdr = snd[e], rvr = rcv[e];
            const float* hxrow = hxb + sdr * HX_STRIDE;
            float* zrow = s_f + rvr * SF_STRIDE + zoff;
            #pragma unroll
            for (int j = 0; j < TPS; ++j) {
                float a = wb2[j];
                #pragma unroll
                for (int k = 0; k < TPS; ++k) a += h1[k] * ww2[k * TPS + j];
                atomicAdd(&zrow[j], a * hxrow[j]);
            }
        }
    }
    __syncthreads();

    // ---------------- Phase D: scale z by 1/8, 1/15, 1/16 ----------------
    #pragma unroll
    for (int i = 0; i < 12; ++i) {
        int idx = tid + i * 256;
        int r = idx / 96, c = idx - r * 96;
        float sc = (c < 32) ? 0.125f : ((c < 64) ? (1.f / 15.f) : (1.f / 16.f));
        s_f[r * SF_STRIDE + 256 + c] *= sc;
    }
    __syncthreads();

    // ---------------- Phase E: out = elec + mlp(f, g) ; 2 halves of 16 rows ----------------
    const float gb1 = g_b1[tid];
    const float gb2 = g_b2[tid];
    for (int half = 0; half < 2; ++half) {
        const int R0 = half * 16;
        float acc[16];
        #pragma unroll
        for (int r = 0; r < 16; ++r) acc[r] = gb1;
        for (int k = 0; k < 352; k += 4) {
            float w0 = g_w1[(size_t)(k + 0) * EMB + tid];
            float w1v = g_w1[(size_t)(k + 1) * EMB + tid];
            float w2v = g_w1[(size_t)(k + 2) * EMB + tid];
            float w3v = g_w1[(size_t)(k + 3) * EMB + tid];
            #pragma unroll
            for (int r = 0; r < 16; ++r) {
                float4 fv = *reinterpret_cast<const float4*>(&s_f[(R0 + r) * SF_STRIDE + k]);
                acc[r] += fv.x * w0 + fv.y * w1v + fv.z * w2v + fv.w * w3v;
            }
        }
        #pragma unroll
        for (int r = 0; r < 16; ++r) s_b[r * 256 + tid] = tanhf(acc[r]);
        __syncthreads();

        float acc2[16];
        #pragma unroll
        for (int r = 0; r < 16; ++r) acc2[r] = gb2;
        for (int k = 0; k < 256; k += 4) {
            float w0 = g_w2[(size_t)(k + 0) * EMB + tid];
            float w1v = g_w2[(size_t)(k + 1) * EMB + tid];
            float w2v = g_w2[(size_t)(k + 2) * EMB + tid];
            float w3v = g_w2[(size_t)(k + 3) * EMB + tid];
            #pragma unroll
            for (int r = 0; r < 16; ++r) {
                float4 hv = *reinterpret_cast<const float4*>(&s_b[r * 256 + k]);
                acc2[r] += hv.x * w0 + hv.y * w1v + hv.z * w2v + hv.w * w3v;
            }
        }
        #pragma unroll
        for (int r = 0; r < 16; ++r) {
            size_t o = ((size_t)b * NE + R0 + r) * EMB + tid;
            out[o] = elec[o] + acc2[r];
        }
        __syncthreads();
    }
}

extern "C" void kernel_launch(void* const* d_in, const int* in_sizes, int n_in,
                              void* d_out, int out_size, void* d_ws, size_t ws_size,
                              hipStream_t stream) {
    const float* elec = (const float*)d_in[0];
    const float* nuc  = (const float*)d_in[1];
    const float* fs   = (const float*)d_in[2];
    const float* fa   = (const float*)d_in[3];
    const float* fn   = (const float*)d_in[4];
    const float* u_w1 = (const float*)d_in[5];
    const float* u_b1 = (const float*)d_in[6];
    const float* u_w2 = (const float*)d_in[7];
    const float* u_b2 = (const float*)d_in[8];
    const float* w_w1 = (const float*)d_in[9];
    const float* w_b1 = (const float*)d_in[10];
    const float* w_w2 = (const float*)d_in[11];
    const float* w_b2 = (const float*)d_in[12];
    const float* h_w1 = (const float*)d_in[13];
    const float* h_b1 = (const float*)d_in[14];
    const float* h_w2 = (const float*)d_in[15];
    const float* h_b2 = (const float*)d_in[16];
    const float* g_w1 = (const float*)d_in[17];
    const float* g_b1 = (const float*)d_in[18];
    const float* g_w2 = (const float*)d_in[19];
    const float* g_b2 = (const float*)d_in[20];
    const int* ss = (const int*)d_in[21];
    const int* rs = (const int*)d_in[22];
    const int* sa = (const int*)d_in[23];
    const int* ra = (const int*)d_in[24];
    const int* sn = (const int*)d_in[25];
    const int* rn = (const int*)d_in[26];

    int nb = in_sizes[0] / (NE * EMB);   // = 2048
    gnn_kernel<<<nb, 256, 0, stream>>>(elec, nuc, fs, fa, fn,
        u_w1, u_b1, u_w2, u_b2, w_w1, w_b1, w_w2, w_b2,
        h_w1, h_b1, h_w2, h_b2, g_w1, g_b1, g_w2, g_b2,
        ss, rs, sa, ra, sn, rn, (float*)d_out);
}

// Round 2
// 507.609 us; speedup vs baseline: 32.8031x; 32.8031x over previous
//
#include <hip/hip_runtime.h>
#include <math.h>

#define NE    32       // N_ELEC
#define NN    8        // N_NUC
#define EMB   256
#define TPS   32
#define E_SAME 480
#define E_ANTI 512
#define E_NE   256

typedef float f32x4 __attribute__((ext_vector_type(4)));
typedef short s16x8 __attribute__((ext_vector_type(8)));

__device__ __forceinline__ short f2bf(float x) {
    unsigned u = __builtin_bit_cast(unsigned, x);
    u += 0x7fffu + ((u >> 16) & 1u);
    return (short)(u >> 16);
}
__device__ __forceinline__ float bf2f(short h) {
    unsigned u = ((unsigned)(unsigned short)h) << 16;
    return __builtin_bit_cast(float, u);
}
__device__ __forceinline__ float fast_tanh(float x) {
    // tanh(x) = 1 - 2/(exp(2x)+1); exp(2x) = exp2(x * 2/ln2)
    float e = __builtin_amdgcn_exp2f(x * 2.8853900817779268f);
    return 1.f - 2.f * __builtin_amdgcn_rcpf(e + 1.f);
}

// ---- ws layout (bf16 shorts), B-fragment-tiled: tile = 512 shorts, frag = wsb[tile + lane*8 + i]
//      frag semantics: b[i] = W[k0 + (lane>>4)*8 + i][n0 + (lane&15)], W row-major [K][N]
// U1: t*1024 + nt*512                      (3 mats 32x32)      [0,     3072)
// U2: 3072  + t*1024 + nt*512                                  [3072,  6144)
// W1: 6144  + ...                                              [6144,  9216)
// W2: 9216  + ...                                              [9216, 12288)
// H1: 12288 + t*8192 + (nt*8+ks)*512       (3 mats 256x32)     [12288, 36864)
// G1: 36864 + (nt*11+ks)*512               (352x256)           [36864, 126976)
// G2: 126976 + (nt*8+ks)*512               (256x256)           [126976, 192512)
#define WS_SHORTS 192512

__global__ void prep_weights(const float* __restrict__ u_w1, const float* __restrict__ u_w2,
                             const float* __restrict__ w_w1, const float* __restrict__ w_w2,
                             const float* __restrict__ h_w1, const float* __restrict__ g_w1,
                             const float* __restrict__ g_w2, short* __restrict__ wsb)
{
    int tile = blockIdx.x, lane = threadIdx.x;
    const float* src; int N, ks, nt, dst;
    if (tile < 24) {
        int m = tile / 6, r = tile % 6, t = r >> 1; nt = r & 1; ks = 0;
        const float* mp = (m == 0) ? u_w1 : (m == 1) ? u_w2 : (m == 2) ? w_w1 : w_w2;
        src = mp + t * 1024; N = 32; dst = m * 3072 + t * 1024 + nt * 512;
    } else if (tile < 72) {
        int i = tile - 24; int t = i >> 4, r = i & 15; nt = r >> 3; ks = r & 7;
        src = h_w1 + t * 8192; N = 32; dst = 12288 + t * 8192 + (nt * 8 + ks) * 512;
    } else if (tile < 248) {
        int i = tile - 72; nt = i / 11; ks = i - nt * 11;
        src = g_w1; N = 256; dst = 36864 + i * 512;
    } else {
        int i = tile - 248; nt = i >> 3; ks = i & 7;
        src = g_w2; N = 256; dst = 126976 + i * 512;
    }
    int kb = ks * 32 + (lane >> 4) * 8, n = nt * 16 + (lane & 15);
    s16x8 v;
    #pragma unroll
    for (int i = 0; i < 8; ++i) v[i] = f2bf(src[(size_t)(kb + i) * N + n]);
    *(s16x8*)(wsb + dst + lane * 8) = v;
}

// LDS map (65440 B total):
//  [0, 23040)      : f bf16 [32][360]  (phase E)  /  also elec-bf16 stash target in phase A
//  [23040, 35456)  : z f32  [32][97]              /  phase E: H bf16 [32][264] overlays [23040,39936)
//  [35456, 44960)  : hx f32 [72][33]
//  [44960, 65440)  : per-wave bounce: wave w -> 1280 shorts (Fbuf [16][40], Bbuf [16][40])
//                    phase A: Y bf16 [80][40] overlays this region
__launch_bounds__(512, 4)
__global__ void gnn_kernel(
    const float* __restrict__ elec, const float* __restrict__ nuc,
    const float* __restrict__ fs,  const float* __restrict__ fa,  const float* __restrict__ fn,
    const float* __restrict__ u_b1, const float* __restrict__ u_b2,
    const float* __restrict__ w_b1, const float* __restrict__ w_b2,
    const float* __restrict__ h_b1, const float* __restrict__ h_w2, const float* __restrict__ h_b2,
    const float* __restrict__ g_b1, const float* __restrict__ g_b2,
    const int* __restrict__ ss, const int* __restrict__ rs,
    const int* __restrict__ sa, const int* __restrict__ ra,
    const int* __restrict__ sn, const int* __restrict__ rn,
    const short* __restrict__ wsb,
    float* __restrict__ out)
{
    __shared__ __align__(16) char smem[65440];
    short* f_s  = (short*)smem;                  // [32][360]
    float* z_s  = (float*)(smem + 23040);        // [32][97]
    float* hx_s = (float*)(smem + 35456);        // [72][33]
    short* H_s  = (short*)(smem + 23040);        // [32][264] (phase E overlay)
    short* Y_s  = (short*)(smem + 44960);        // [80][40]  (phase A overlay)

    const int tid  = threadIdx.x;
    const int b    = blockIdx.x;
    const int lane = tid & 63, wv = tid >> 6;
    const int g    = lane >> 4, q = lane & 15;
    short* wb = (short*)(smem + 44960) + wv * 1280;  // Fbuf = wb, Bbuf = wb+640

    // ================= Phase A layer 1 (MFMA): Y = tanh(X @ h_w1[t] + h_b1[t]) =================
    for (int task = wv; task < 10; task += 8) {
        int t, mt, nt;
        if (task < 8) { t = task >> 2; mt = (task >> 1) & 1; nt = task & 1; }
        else          { t = 2; mt = 0; nt = task & 1; }
        const float* src; int row;
        if (t < 2) { row = mt * 16 + q; src = elec + ((size_t)b * NE + row) * EMB; }
        else       { row = (q < 7) ? q : 7; src = nuc + ((size_t)b * NN + row) * EMB; }
        f32x4 acc = {0.f, 0.f, 0.f, 0.f};
        #pragma unroll
        for (int ks = 0; ks < 8; ++ks) {
            int k0 = ks * 32 + g * 8;
            float4 v0 = *(const float4*)(src + k0);
            float4 v1 = *(const float4*)(src + k0 + 4);
            s16x8 a = { f2bf(v0.x), f2bf(v0.y), f2bf(v0.z), f2bf(v0.w),
                        f2bf(v1.x), f2bf(v1.y), f2bf(v1.z), f2bf(v1.w) };
            s16x8 bw = *(const s16x8*)(wsb + 12288 + t * 8192 + (nt * 8 + ks) * 512 + lane * 8);
            acc = __builtin_amdgcn_mfma_f32_16x16x32_bf16(a, bw, acc, 0, 0, 0);
            if (t == 0 && nt == 0)  // stash elec bf16 into f (cols 0..255)
                *(s16x8*)(f_s + row * 360 + k0) = a;
        }
        float bias = h_b1[t * 32 + nt * 16 + q];
        int yr = t * 32 + mt * 16 + 4 * g;
        #pragma unroll
        for (int r = 0; r < 4; ++r)
            Y_s[(yr + r) * 40 + nt * 16 + q] = f2bf(fast_tanh(acc[r] + bias));
    }
    __syncthreads();

    // ================= Phase A layer 2 (VALU): hx = Y @ h_w2[t] + h_b2[t] ; zero z ============
    for (int i = tid; i < 72 * 32; i += 512) {
        int n = i >> 5, j = i & 31;
        int t = n >> 5;
        float a = h_b2[t * 32 + j];
        const float* w = h_w2 + t * 1024 + j;
        const short* yrow = Y_s + n * 40;
        #pragma unroll
        for (int k = 0; k < 32; ++k) a += bf2f(yrow[k]) * w[k * 32];
        hx_s[n * 33 + j] = a;
    }
    for (int i = tid; i < 32 * 97; i += 512) z_s[i] = 0.f;
    __syncthreads();

    // ================= Phase C: edge MLPs (per-wave 16-edge MFMA tiles) ========================
    short* Fb = wb;
    short* Bb = wb + 640;
    for (int t = 0; t < 3; ++t) {
        const float* ft; const int* snd; const int* rcv; int cnt, zc0;
        if (t == 0)      { ft = fs; snd = ss; rcv = rs; cnt = E_SAME; zc0 = 32; }
        else if (t == 1) { ft = fa; snd = sa; rcv = ra; cnt = E_ANTI; zc0 = 64; }
        else             { ft = fn; snd = sn; rcv = rn; cnt = E_NE;   zc0 = 0;  }
        // hoisted per-type weight fragments + biases
        s16x8 bu1[2], bu2[2], bw1[2], bw2[2];
        float vb1[2], vb2[2], vb3[2], vb4[2];
        #pragma unroll
        for (int nt = 0; nt < 2; ++nt) {
            int off = t * 1024 + nt * 512 + lane * 8;
            bu1[nt] = *(const s16x8*)(wsb + off);
            bu2[nt] = *(const s16x8*)(wsb + 3072 + off);
            bw1[nt] = *(const s16x8*)(wsb + 6144 + off);
            bw2[nt] = *(const s16x8*)(wsb + 9216 + off);
            int col = t * 32 + nt * 16 + q;
            vb1[nt] = u_b1[col]; vb2[nt] = u_b2[col];
            vb3[nt] = w_b1[col]; vb4[nt] = w_b2[col];
        }
        const float* hxt = hx_s + t * 32 * 33;
        int ntile = cnt >> 4;
        for (int tt = wv; tt < ntile; tt += 8) {
            int e0 = tt << 4;
            const float* fp = ft + ((size_t)b * cnt + e0 + q) * TPS + g * 8;
            float4 v0 = *(const float4*)fp;
            float4 v1 = *(const float4*)(fp + 4);
            s16x8 aF = { f2bf(v0.x), f2bf(v0.y), f2bf(v0.z), f2bf(v0.w),
                         f2bf(v1.x), f2bf(v1.y), f2bf(v1.z), f2bf(v1.w) };
            *(s16x8*)(Fb + q * 40 + g * 8) = aF;
            // u layer 1
            f32x4 z4 = {0.f, 0.f, 0.f, 0.f};
            f32x4 a0 = __builtin_amdgcn_mfma_f32_16x16x32_bf16(aF, bu1[0], z4, 0, 0, 0);
            f32x4 a1 = __builtin_amdgcn_mfma_f32_16x16x32_bf16(aF, bu1[1], z4, 0, 0, 0);
            #pragma unroll
            for (int r = 0; r < 4; ++r) {
                Bb[(4 * g + r) * 40 + q]      = f2bf(fast_tanh(a0[r] + vb1[0]));
                Bb[(4 * g + r) * 40 + 16 + q] = f2bf(fast_tanh(a1[r] + vb1[1]));
            }
            s16x8 aH = *(const s16x8*)(Bb + q * 40 + g * 8);
            // u layer 2 + residual
            a0 = __builtin_amdgcn_mfma_f32_16x16x32_bf16(aH, bu2[0], z4, 0, 0, 0);
            a1 = __builtin_amdgcn_mfma_f32_16x16x32_bf16(aH, bu2[1], z4, 0, 0, 0);
            #pragma unroll
            for (int r = 0; r < 4; ++r) {
                float fc0 = bf2f(Fb[(4 * g + r) * 40 + q]);
                float fc1 = bf2f(Fb[(4 * g + r) * 40 + 16 + q]);
                Bb[(4 * g + r) * 40 + q]      = f2bf(fc0 + a0[r] + vb2[0]);
                Bb[(4 * g + r) * 40 + 16 + q] = f2bf(fc1 + a1[r] + vb2[1]);
            }
            aH = *(const s16x8*)(Bb + q * 40 + g * 8);
            // w layer 1
            a0 = __builtin_amdgcn_mfma_f32_16x16x32_bf16(aH, bw1[0], z4, 0, 0, 0);
            a1 = __builtin_amdgcn_mfma_f32_16x16x32_bf16(aH, bw1[1], z4, 0, 0, 0);
            #pragma unroll
            for (int r = 0; r < 4; ++r) {
                Bb[(4 * g + r) * 40 + q]      = f2bf(fast_tanh(a0[r] + vb3[0]));
                Bb[(4 * g + r) * 40 + 16 + q] = f2bf(fast_tanh(a1[r] + vb3[1]));
            }
            aH = *(const s16x8*)(Bb + q * 40 + g * 8);
            // w layer 2 -> we (C-layout regs)
            a0 = __builtin_amdgcn_mfma_f32_16x16x32_bf16(aH, bw2[0], z4, 0, 0, 0);
            a1 = __builtin_amdgcn_mfma_f32_16x16x32_bf16(aH, bw2[1], z4, 0, 0, 0);
            // msg = we * hx[sender] ; scatter-add into z[receiver]
            int4 s4 = *(const int4*)(snd + e0 + 4 * g);
            int4 r4 = *(const int4*)(rcv + e0 + 4 * g);
            const int* sp = (const int*)&s4;
            const int* rp = (const int*)&r4;
            #pragma unroll
            for (int r = 0; r < 4; ++r) {
                int sv = sp[r], rv = rp[r];
                float we0 = a0[r] + vb4[0];
                float we1 = a1[r] + vb4[1];
                atomicAdd(&z_s[rv * 97 + zc0 + q],      we0 * hxt[sv * 33 + q]);
                atomicAdd(&z_s[rv * 97 + zc0 + 16 + q], we1 * hxt[sv * 33 + 16 + q]);
            }
        }
    }
    __syncthreads();

    // ================= Phase D: f[:,256:352] = z * scale (bf16) =================
    for (int i = tid; i < 32 * 96; i += 512) {
        int r = i / 96, c = i - r * 96;
        float sc = (c < 32) ? 0.125f : ((c < 64) ? (1.f / 15.f) : (1.f / 16.f));
        f_s[r * 360 + 256 + c] = f2bf(z_s[r * 97 + c] * sc);
    }
    __syncthreads();

    // ================= Phase E layer 1 (MFMA): H = tanh(f @ g_w1 + g_b1) =================
    for (int task = wv; task < 32; task += 8) {
        int mt = task >> 4, nt = task & 15;
        f32x4 acc = {0.f, 0.f, 0.f, 0.f};
        const short* arow = f_s + (mt * 16 + q) * 360 + g * 8;
        const short* wp = wsb + 36864 + nt * 11 * 512 + lane * 8;
        #pragma unroll
        for (int ks = 0; ks < 11; ++ks) {
            s16x8 a  = *(const s16x8*)(arow + ks * 32);
            s16x8 bw = *(const s16x8*)(wp + ks * 512);
            acc = __builtin_amdgcn_mfma_f32_16x16x32_bf16(a, bw, acc, 0, 0, 0);
        }
        float bias = g_b1[nt * 16 + q];
        #pragma unroll
        for (int r = 0; r < 4; ++r)
            H_s[(mt * 16 + 4 * g + r) * 264 + nt * 16 + q] = f2bf(fast_tanh(acc[r] + bias));
    }
    __syncthreads();

    // ================= Phase E layer 2 (MFMA): out = elec + H @ g_w2 + g_b2 =================
    for (int task = wv; task < 32; task += 8) {
        int mt = task >> 4, nt = task & 15;
        f32x4 acc = {0.f, 0.f, 0.f, 0.f};
        const short* arow = H_s + (mt * 16 + q) * 264 + g * 8;
        const short* wp = wsb + 126976 + nt * 8 * 512 + lane * 8;
        #pragma unroll
        for (int ks = 0; ks < 8; ++ks) {
            s16x8 a  = *(const s16x8*)(arow + ks * 32);
            s16x8 bw = *(const s16x8*)(wp + ks * 512);
            acc = __builtin_amdgcn_mfma_f32_16x16x32_bf16(a, bw, acc, 0, 0, 0);
        }
        float bias = g_b2[nt * 16 + q];
        #pragma unroll
        for (int r = 0; r < 4; ++r) {
            int row = mt * 16 + 4 * g + r, col = nt * 16 + q;
            size_t o = ((size_t)b * NE + row) * EMB + col;
            out[o] = bf2f(f_s[row * 360 + col]) + acc[r] + bias;
        }
    }
}

extern "C" void kernel_launch(void* const* d_in, const int* in_sizes, int n_in,
                              void* d_out, int out_size, void* d_ws, size_t ws_size,
                              hipStream_t stream) {
    const float* elec = (const float*)d_in[0];
    const float* nuc  = (const float*)d_in[1];
    const float* fs   = (const float*)d_in[2];
    const float* fa   = (const float*)d_in[3];
    const float* fn   = (const float*)d_in[4];
    const float* u_w1 = (const float*)d_in[5];
    const float* u_b1 = (const float*)d_in[6];
    const float* u_w2 = (const float*)d_in[7];
    const float* u_b2 = (const float*)d_in[8];
    const float* w_w1 = (const float*)d_in[9];
    const float* w_b1 = (const float*)d_in[10];
    const float* w_w2 = (const float*)d_in[11];
    const float* w_b2 = (const float*)d_in[12];
    const float* h_w1 = (const float*)d_in[13];
    const float* h_b1 = (const float*)d_in[14];
    const float* h_w2 = (const float*)d_in[15];
    const float* h_b2 = (const float*)d_in[16];
    const float* g_w1 = (const float*)d_in[17];
    const float* g_b1 = (const float*)d_in[18];
    const float* g_w2 = (const float*)d_in[19];
    const float* g_b2 = (const float*)d_in[20];
    const int* ss = (const int*)d_in[21];
    const int* rs = (const int*)d_in[22];
    const int* sa = (const int*)d_in[23];
    const int* ra = (const int*)d_in[24];
    const int* sn = (const int*)d_in[25];
    const int* rn = (const int*)d_in[26];

    short* wsb = (short*)d_ws;
    int nb = in_sizes[0] / (NE * EMB);

    prep_weights<<<376, 64, 0, stream>>>(u_w1, u_w2, w_w1, w_w2, h_w1, g_w1, g_w2, wsb);
    gnn_kernel<<<nb, 512, 0, stream>>>(elec, nuc, fs, fa, fn,
        u_b1, u_b2, w_b1, w_b2, h_b1, h_w2, h_b2, g_b1, g_b2,
        ss, rs, sa, ra, sn, rn, wsb, (float*)d_out);
}

// Round 3
// 476.027 us; speedup vs baseline: 34.9793x; 1.0663x over previous
//
#include <hip/hip_runtime.h>
#include <math.h>

#define NE 32
#define NN 8
#define EMB 256
#define TPS 32
#define E_SAME 480
#define E_ANTI 512
#define E_NE 256

// ---- ws layout (shorts) ----
#define AU1_OFF 0        // 6  x 512 : u_w1^T K=32 A-frags, idx (t*2+mt)
#define AU2_OFF 3072     // 12 x 256 : u_w2^T K=16 A-frags, idx (t*4+mt*2+ks)
#define AW1_OFF 6144     // 12 x 256 : w_w1^T
#define AW2_OFF 9216     // 12 x 256 : w_w2^T
#define H1T_OFF 12288    // 48 x 512 : h_w1^T K=32, idx (t*16+mt*8+ks)
#define H2T_OFF 36864    // 12 x 256 : h_w2^T K=16, idx (t*4+mt*2+ks)
#define BIAS_OFF 39936   // 576 bf16 : [L][t][32], L: u_b1,u_b2,w_b1,w_b2,h_b1,h_b2
#define G1_OFF 40512     // 176 x 512: g_w1 B-frags K=32, idx (nt*11+ks)
#define G2_OFF 130624    // 128 x 512: g_w2 B-frags K=32, idx (nt*8+ks)
// total 196160 shorts = 392320 B

typedef float f32x4 __attribute__((ext_vector_type(4)));
typedef short s16x4 __attribute__((ext_vector_type(4)));
typedef short s16x8 __attribute__((ext_vector_type(8)));

__device__ __forceinline__ short f2bf(float x) {
    unsigned u = __builtin_bit_cast(unsigned, x);
    u += 0x7fffu + ((u >> 16) & 1u);
    return (short)(u >> 16);
}
__device__ __forceinline__ float bf2f(short h) {
    unsigned u = ((unsigned)(unsigned short)h) << 16;
    return __builtin_bit_cast(float, u);
}
__device__ __forceinline__ float fast_tanh(float x) {
    float e = __builtin_amdgcn_exp2f(x * 2.8853900817779268f);
    return 1.f - 2.f * __builtin_amdgcn_rcpf(e + 1.f);
}
__device__ __forceinline__ s16x8 pack8(float4 a, float4 b) {
    s16x8 r = { f2bf(a.x), f2bf(a.y), f2bf(a.z), f2bf(a.w),
                f2bf(b.x), f2bf(b.y), f2bf(b.z), f2bf(b.w) };
    return r;
}
__device__ __forceinline__ f32x4 mfma32(s16x8 a, s16x8 b, f32x4 c) {
    return __builtin_amdgcn_mfma_f32_16x16x32_bf16(a, b, c, 0, 0, 0);
}
// 16x16x16 bf16: C/D layout == B layout -> chained layers need no lane shuffles.
__device__ __forceinline__ f32x4 mfma16(s16x4 a, s16x4 b, f32x4 c) {
    asm("v_mfma_f32_16x16x16_bf16 %0, %1, %2, %0" : "+v"(c) : "v"(a), "v"(b));
    return c;
}

__global__ void prep_weights(const float* __restrict__ u_w1, const float* __restrict__ u_w2,
                             const float* __restrict__ w_w1, const float* __restrict__ w_w2,
                             const float* __restrict__ h_w1, const float* __restrict__ h_w2,
                             const float* __restrict__ u_b1, const float* __restrict__ u_b2,
                             const float* __restrict__ w_b1, const float* __restrict__ w_b2,
                             const float* __restrict__ h_b1, const float* __restrict__ h_b2,
                             const float* __restrict__ g_w1, const float* __restrict__ g_w2,
                             short* __restrict__ wsb)
{
    int tile = blockIdx.x, lane = threadIdx.x;
    int g = lane >> 4, q = lane & 15;
    if (tile < 6) {                         // Au1: K=32 A-frag of u_w1^T
        int t = tile >> 1, mt = tile & 1;
        const float* src = u_w1 + t * 1024;
        short* dst = wsb + AU1_OFF + tile * 512 + lane * 8;
        #pragma unroll
        for (int i = 0; i < 8; ++i) dst[i] = f2bf(src[(8 * g + i) * 32 + mt * 16 + q]);
    } else if (tile < 42) {                 // Au2/Aw1/Aw2: K=16 A-frags
        int m = (tile - 6) / 12, idx = (tile - 6) % 12;
        int mt = (idx >> 1) & 1, ks = idx & 1, t = idx >> 2;
        const float* mp = (m == 0) ? u_w2 : (m == 1) ? w_w1 : w_w2;
        const float* src = mp + t * 1024;
        short* dst = wsb + AU2_OFF + m * 3072 + idx * 256 + lane * 4;
        #pragma unroll
        for (int i = 0; i < 4; ++i) dst[i] = f2bf(src[(ks * 16 + 4 * g + i) * 32 + mt * 16 + q]);
    } else if (tile < 90) {                 // h1T: K=32 A-frags
        int idx = tile - 42;
        int t = idx >> 4, r = idx & 15, mt = r >> 3, ks = r & 7;
        const float* src = h_w1 + t * 8192;
        short* dst = wsb + H1T_OFF + idx * 512 + lane * 8;
        #pragma unroll
        for (int i = 0; i < 8; ++i) dst[i] = f2bf(src[(ks * 32 + 8 * g + i) * 32 + mt * 16 + q]);
    } else if (tile < 102) {                // h2T: K=16 A-frags
        int idx = tile - 90;
        int t = idx >> 2, mt = (idx >> 1) & 1, ks = idx & 1;
        const float* src = h_w2 + t * 1024;
        short* dst = wsb + H2T_OFF + idx * 256 + lane * 4;
        #pragma unroll
        for (int i = 0; i < 4; ++i) dst[i] = f2bf(src[(ks * 16 + 4 * g + i) * 32 + mt * 16 + q]);
    } else if (tile == 102) {               // biases -> bf16 [L][t][32]
        const float* bsrc[6] = {u_b1, u_b2, w_b1, w_b2, h_b1, h_b2};
        for (int j = lane; j < 576; j += 64)
            wsb[BIAS_OFF + j] = f2bf(bsrc[j / 96][j % 96]);
    } else if (tile < 279) {                // G1 B-frags
        int idx = tile - 103, nt = idx / 11, ks = idx % 11;
        short* dst = wsb + G1_OFF + idx * 512 + lane * 8;
        #pragma unroll
        for (int i = 0; i < 8; ++i)
            dst[i] = f2bf(g_w1[(size_t)(ks * 32 + 8 * g + i) * 256 + nt * 16 + q]);
    } else {                                // G2 B-frags
        int idx = tile - 279;
        short* dst = wsb + G2_OFF + idx * 512 + lane * 8;
        int nt = idx >> 3, ks = idx & 7;
        #pragma unroll
        for (int i = 0; i < 8; ++i)
            dst[i] = f2bf(g_w2[(size_t)(ks * 32 + 8 * g + i) * 256 + nt * 16 + q]);
    }
}

// LDS: f bf16 [32][356] = 22784 ; z f32 [32][97] = 12416 ; hx bf16 [72][36] = 5184
// phase E: H bf16 [32][260] = 16640 overlays z+hx. Total 40384 B -> 4 blocks/CU.
__launch_bounds__(256, 4)
__global__ void gnn_kernel(
    const float* __restrict__ elec, const float* __restrict__ nuc,
    const float* __restrict__ fs,  const float* __restrict__ fa,  const float* __restrict__ fn,
    const float* __restrict__ g_b1, const float* __restrict__ g_b2,
    const int* __restrict__ ss, const int* __restrict__ rs,
    const int* __restrict__ sa, const int* __restrict__ ra,
    const int* __restrict__ sn, const int* __restrict__ rn,
    const short* __restrict__ wsb,
    float* __restrict__ out)
{
    __shared__ __align__(16) char smem[40384];
    short* f_s  = (short*)smem;                  // [32][356]
    float* z_s  = (float*)(smem + 22784);        // [32][97]
    short* hx_s = (short*)(smem + 35200);        // [72][36]
    short* H_s  = (short*)(smem + 22784);        // [32][260] (phase E overlay)

    const int tid  = threadIdx.x;
    const int b    = blockIdx.x;
    const int lane = tid & 63, wv = tid >> 6;
    const int g    = lane >> 4, q = lane & 15;

    // ---------- Phase A: hx^T = h_w2^T @ tanh(h_w1^T @ X^T + b1) + b2 ----------
    if (wv > 0)
        for (int i = tid - 64; i < 32 * 97; i += 192) z_s[i] = 0.f;

    #pragma unroll 1
    for (int task = wv; task < 5; task += 4) {
        int t, nt;
        if (task < 4) { t = task >> 1; nt = task & 1; }
        else          { t = 2; nt = 0; }
        const float* rowp = (t < 2) ? elec + ((size_t)b * NE + nt * 16 + q) * EMB
                                    : nuc  + ((size_t)b * NN + (q < 8 ? q : 7)) * EMB;
        f32x4 c0 = {0.f, 0.f, 0.f, 0.f}, c1 = {0.f, 0.f, 0.f, 0.f};
        const short* wA = wsb + H1T_OFF + t * 16 * 512;
        #pragma unroll
        for (int ks = 0; ks < 8; ++ks) {
            float4 v0 = *(const float4*)(rowp + 32 * ks + 8 * g);
            float4 v1 = *(const float4*)(rowp + 32 * ks + 8 * g + 4);
            s16x8 Bf = pack8(v0, v1);
            if (t == 0) {   // stash elec bf16 into f cols 0..255
                int off = (nt * 16 + q) * 356 + 32 * ks + 8 * g;
                *(s16x4*)(f_s + off)     = __builtin_shufflevector(Bf, Bf, 0, 1, 2, 3);
                *(s16x4*)(f_s + off + 4) = __builtin_shufflevector(Bf, Bf, 4, 5, 6, 7);
            }
            s16x8 a0 = *(const s16x8*)(wA + ks * 512 + lane * 8);
            s16x8 a1 = *(const s16x8*)(wA + (8 + ks) * 512 + lane * 8);
            c0 = mfma32(a0, Bf, c0);
            c1 = mfma32(a1, Bf, c1);
        }
        s16x4 b1l = *(const s16x4*)(wsb + BIAS_OFF + (12 + t) * 32 + 4 * g);
        s16x4 b1h = *(const s16x4*)(wsb + BIAS_OFF + (12 + t) * 32 + 16 + 4 * g);
        s16x4 p0, p1;
        #pragma unroll
        for (int r = 0; r < 4; ++r) {
            p0[r] = f2bf(fast_tanh(c0[r] + bf2f(b1l[r])));
            p1[r] = f2bf(fast_tanh(c1[r] + bf2f(b1h[r])));
        }
        const short* wA2 = wsb + H2T_OFF + t * 4 * 256;
        f32x4 d0 = {0.f, 0.f, 0.f, 0.f}, d1 = {0.f, 0.f, 0.f, 0.f};
        d0 = mfma16(*(const s16x4*)(wA2 + 0 * 256 + lane * 4), p0, d0);
        d0 = mfma16(*(const s16x4*)(wA2 + 1 * 256 + lane * 4), p1, d0);
        d1 = mfma16(*(const s16x4*)(wA2 + 2 * 256 + lane * 4), p0, d1);
        d1 = mfma16(*(const s16x4*)(wA2 + 3 * 256 + lane * 4), p1, d1);
        if (t < 2 || q < 8) {
            s16x4 b2l = *(const s16x4*)(wsb + BIAS_OFF + (15 + t) * 32 + 4 * g);
            s16x4 b2h = *(const s16x4*)(wsb + BIAS_OFF + (15 + t) * 32 + 16 + 4 * g);
            s16x4 w0, w1;
            #pragma unroll
            for (int r = 0; r < 4; ++r) {
                w0[r] = f2bf(d0[r] + bf2f(b2l[r]));
                w1[r] = f2bf(d1[r] + bf2f(b2h[r]));
            }
            int row = t * 32 + nt * 16 + q;
            *(s16x4*)(hx_s + row * 36 + 4 * g)      = w0;
            *(s16x4*)(hx_s + row * 36 + 16 + 4 * g) = w1;
        }
    }
    __syncthreads();

    // ---------- Phase C: edge MLPs, fully register-chained ----------
    #pragma unroll 1
    for (int t = 0; t < 3; ++t) {
        const float* ft; const int* snd; const int* rcv; int cnt, zc0;
        if (t == 0)      { ft = fs; snd = ss; rcv = rs; cnt = E_SAME; zc0 = 32; }
        else if (t == 1) { ft = fa; snd = sa; rcv = ra; cnt = E_ANTI; zc0 = 64; }
        else             { ft = fn; snd = sn; rcv = rn; cnt = E_NE;   zc0 = 0;  }
        s16x8 Au1_0 = *(const s16x8*)(wsb + AU1_OFF + (t * 2 + 0) * 512 + lane * 8);
        s16x8 Au1_1 = *(const s16x8*)(wsb + AU1_OFF + (t * 2 + 1) * 512 + lane * 8);
        s16x4 Au2_[4], Aw1_[4], Aw2_[4];
        #pragma unroll
        for (int i = 0; i < 4; ++i) {
            Au2_[i] = *(const s16x4*)(wsb + AU2_OFF + (t * 4 + i) * 256 + lane * 4);
            Aw1_[i] = *(const s16x4*)(wsb + AW1_OFF + (t * 4 + i) * 256 + lane * 4);
            Aw2_[i] = *(const s16x4*)(wsb + AW2_OFF + (t * 4 + i) * 256 + lane * 4);
        }
        s16x4 bb1l = *(const s16x4*)(wsb + BIAS_OFF + (0 + t) * 32 + 4 * g);
        s16x4 bb1h = *(const s16x4*)(wsb + BIAS_OFF + (0 + t) * 32 + 16 + 4 * g);
        s16x4 bb2l = *(const s16x4*)(wsb + BIAS_OFF + (3 + t) * 32 + 4 * g);
        s16x4 bb2h = *(const s16x4*)(wsb + BIAS_OFF + (3 + t) * 32 + 16 + 4 * g);
        s16x4 bb3l = *(const s16x4*)(wsb + BIAS_OFF + (6 + t) * 32 + 4 * g);
        s16x4 bb3h = *(const s16x4*)(wsb + BIAS_OFF + (6 + t) * 32 + 16 + 4 * g);
        s16x4 bb4l = *(const s16x4*)(wsb + BIAS_OFF + (9 + t) * 32 + 4 * g);
        s16x4 bb4h = *(const s16x4*)(wsb + BIAS_OFF + (9 + t) * 32 + 16 + 4 * g);
        const short* hxt = hx_s + t * 32 * 36;
        int ntile = cnt >> 4;

        // prologue loads for first tile
        const float* fp = ft + ((size_t)b * cnt + wv * 16 + q) * TPS;
        float4 v0 = *(const float4*)(fp + 8 * g);
        float4 v1 = *(const float4*)(fp + 8 * g + 4);
        float4 rl = *(const float4*)(fp + 4 * g);
        float4 rh = *(const float4*)(fp + 16 + 4 * g);
        int se = snd[wv * 16 + q], re = rcv[wv * 16 + q];

        #pragma unroll 1
        for (int tt = wv; tt < ntile; tt += 4) {
            int tn = tt + 4;
            float4 n0 = {0,0,0,0}, n1 = {0,0,0,0}, nrl = {0,0,0,0}, nrh = {0,0,0,0};
            int ns = 0, nr = 0;
            if (tn < ntile) {   // prefetch next tile
                const float* np = ft + ((size_t)b * cnt + tn * 16 + q) * TPS;
                n0 = *(const float4*)(np + 8 * g);
                n1 = *(const float4*)(np + 8 * g + 4);
                nrl = *(const float4*)(np + 4 * g);
                nrh = *(const float4*)(np + 16 + 4 * g);
                ns = snd[tn * 16 + q]; nr = rcv[tn * 16 + q];
            }
            s16x8 B32 = pack8(v0, v1);
            // u layer1 (K=32)
            f32x4 c0 = {0.f,0.f,0.f,0.f}, c1 = {0.f,0.f,0.f,0.f};
            c0 = mfma32(Au1_0, B32, c0);
            c1 = mfma32(Au1_1, B32, c1);
            s16x4 p0, p1;
            #pragma unroll
            for (int r = 0; r < 4; ++r) {
                p0[r] = f2bf(fast_tanh(c0[r] + bf2f(bb1l[r])));
                p1[r] = f2bf(fast_tanh(c1[r] + bf2f(bb1h[r])));
            }
            // u layer2 (K=16 x2) + residual (f32 feats)
            f32x4 d0 = {0.f,0.f,0.f,0.f}, d1 = {0.f,0.f,0.f,0.f};
            d0 = mfma16(Au2_[0], p0, d0); d0 = mfma16(Au2_[1], p1, d0);
            d1 = mfma16(Au2_[2], p0, d1); d1 = mfma16(Au2_[3], p1, d1);
            const float* rlp = (const float*)&rl; const float* rhp = (const float*)&rh;
            #pragma unroll
            for (int r = 0; r < 4; ++r) {
                p0[r] = f2bf(rlp[r] + d0[r] + bf2f(bb2l[r]));
                p1[r] = f2bf(rhp[r] + d1[r] + bf2f(bb2h[r]));
            }
            // w layer1
            d0 = (f32x4){0.f,0.f,0.f,0.f}; d1 = (f32x4){0.f,0.f,0.f,0.f};
            d0 = mfma16(Aw1_[0], p0, d0); d0 = mfma16(Aw1_[1], p1, d0);
            d1 = mfma16(Aw1_[2], p0, d1); d1 = mfma16(Aw1_[3], p1, d1);
            #pragma unroll
            for (int r = 0; r < 4; ++r) {
                p0[r] = f2bf(fast_tanh(d0[r] + bf2f(bb3l[r])));
                p1[r] = f2bf(fast_tanh(d1[r] + bf2f(bb3h[r])));
            }
            // w layer2 -> we
            d0 = (f32x4){0.f,0.f,0.f,0.f}; d1 = (f32x4){0.f,0.f,0.f,0.f};
            d0 = mfma16(Aw2_[0], p0, d0); d0 = mfma16(Aw2_[1], p1, d0);
            d1 = mfma16(Aw2_[2], p0, d1); d1 = mfma16(Aw2_[3], p1, d1);
            // msg = we * hx[sender] ; scatter into z[receiver]
            s16x4 hlo = *(const s16x4*)(hxt + se * 36 + 4 * g);
            s16x4 hhi = *(const s16x4*)(hxt + se * 36 + 16 + 4 * g);
            float* zr = z_s + re * 97 + zc0 + 4 * g;
            #pragma unroll
            for (int r = 0; r < 4; ++r) {
                atomicAdd(zr + r,      (d0[r] + bf2f(bb4l[r])) * bf2f(hlo[r]));
                atomicAdd(zr + 16 + r, (d1[r] + bf2f(bb4h[r])) * bf2f(hhi[r]));
            }
            v0 = n0; v1 = n1; rl = nrl; rh = nrh; se = ns; re = nr;
        }
    }
    __syncthreads();

    // ---------- Phase D: f[:,256:352] = z * scale (bf16) ----------
    for (int i = tid; i < 32 * 96; i += 256) {
        int r = i / 96, c = i - r * 96;
        float sc = (c < 32) ? 0.125f : ((c < 64) ? (1.f / 15.f) : (1.f / 16.f));
        f_s[r * 356 + 256 + c] = f2bf(z_s[r * 97 + c] * sc);
    }
    __syncthreads();

    // ---------- Phase E layer1: H = tanh(f @ g_w1 + g_b1) ----------
    #pragma unroll 1
    for (int task = wv; task < 32; task += 4) {
        int mt = task >> 4, nt = task & 15;
        f32x4 acc = {0.f, 0.f, 0.f, 0.f};
        const short* ar = f_s + (mt * 16 + q) * 356 + 8 * g;
        const short* wp = wsb + G1_OFF + nt * 11 * 512 + lane * 8;
        #pragma unroll
        for (int ks = 0; ks < 11; ++ks) {
            s16x4 alo = *(const s16x4*)(ar + 32 * ks);
            s16x4 ahi = *(const s16x4*)(ar + 32 * ks + 4);
            s16x8 a = __builtin_shufflevector(alo, ahi, 0, 1, 2, 3, 4, 5, 6, 7);
            s16x8 bw = *(const s16x8*)(wp + ks * 512);
            acc = mfma32(a, bw, acc);
        }
        float bias = g_b1[nt * 16 + q];
        #pragma unroll
        for (int r = 0; r < 4; ++r)
            H_s[(mt * 16 + 4 * g + r) * 260 + nt * 16 + q] = f2bf(fast_tanh(acc[r] + bias));
    }
    __syncthreads();

    // ---------- Phase E layer2: out = elec + H @ g_w2 + g_b2 ----------
    #pragma unroll 1
    for (int task = wv; task < 32; task += 4) {
        int mt = task >> 4, nt = task & 15;
        f32x4 acc = {0.f, 0.f, 0.f, 0.f};
        const short* ar = H_s + (mt * 16 + q) * 260 + 8 * g;
        const short* wp = wsb + G2_OFF + nt * 8 * 512 + lane * 8;
        #pragma unroll
        for (int ks = 0; ks < 8; ++ks) {
            s16x4 alo = *(const s16x4*)(ar + 32 * ks);
            s16x4 ahi = *(const s16x4*)(ar + 32 * ks + 4);
            s16x8 a = __builtin_shufflevector(alo, ahi, 0, 1, 2, 3, 4, 5, 6, 7);
            s16x8 bw = *(const s16x8*)(wp + ks * 512);
            acc = mfma32(a, bw, acc);
        }
        float bias = g_b2[nt * 16 + q];
        #pragma unroll
        for (int r = 0; r < 4; ++r) {
            int row = mt * 16 + 4 * g + r, col = nt * 16 + q;
            size_t o = ((size_t)b * NE + row) * EMB + col;
            out[o] = bf2f(f_s[row * 356 + col]) + acc[r] + bias;
        }
    }
}

extern "C" void kernel_launch(void* const* d_in, const int* in_sizes, int n_in,
                              void* d_out, int out_size, void* d_ws, size_t ws_size,
                              hipStream_t stream) {
    const float* elec = (const float*)d_in[0];
    const float* nuc  = (const float*)d_in[1];
    const float* fs   = (const float*)d_in[2];
    const float* fa   = (const float*)d_in[3];
    const float* fn   = (const float*)d_in[4];
    const float* u_w1 = (const float*)d_in[5];
    const float* u_b1 = (const float*)d_in[6];
    const float* u_w2 = (const float*)d_in[7];
    const float* u_b2 = (const float*)d_in[8];
    const float* w_w1 = (const float*)d_in[9];
    const float* w_b1 = (const float*)d_in[10];
    const float* w_w2 = (const float*)d_in[11];
    const float* w_b2 = (const float*)d_in[12];
    const float* h_w1 = (const float*)d_in[13];
    const float* h_b1 = (const float*)d_in[14];
    const float* h_w2 = (const float*)d_in[15];
    const float* h_b2 = (const float*)d_in[16];
    const float* g_w1 = (const float*)d_in[17];
    const float* g_b1 = (const float*)d_in[18];
    const float* g_w2 = (const float*)d_in[19];
    const float* g_b2 = (const float*)d_in[20];
    const int* ss = (const int*)d_in[21];
    const int* rs = (const int*)d_in[22];
    const int* sa = (const int*)d_in[23];
    const int* ra = (const int*)d_in[24];
    const int* sn = (const int*)d_in[25];
    const int* rn = (const int*)d_in[26];

    short* wsb = (short*)d_ws;
    int nb = in_sizes[0] / (NE * EMB);

    prep_weights<<<407, 64, 0, stream>>>(u_w1, u_w2, w_w1, w_w2, h_w1, h_w2,
                                         u_b1, u_b2, w_b1, w_b2, h_b1, h_b2,
                                         g_w1, g_w2, wsb);
    gnn_kernel<<<nb, 256, 0, stream>>>(elec, nuc, fs, fa, fn, g_b1, g_b2,
                                       ss, rs, sa, ra, sn, rn, wsb, (float*)d_out);
}

// Round 6
// 473.558 us; speedup vs baseline: 35.1617x; 1.0052x over previous
//
#include <hip/hip_runtime.h>
#include <math.h>

#define NE 32
#define NN 8
#define EMB 256
#define TPS 32
#define E_SAME 480
#define E_ANTI 512
#define E_NE 256

// ---- ws layout (shorts) ----
#define AU1_OFF 0        // 6  x 512 : u_w1^T K=32 A-frags, idx (t*2+mt)
#define AU2_OFF 3072     // 12 x 256 : u_w2^T K=16 A-frags, idx (t*4+mt*2+ks)
#define AW1_OFF 6144     // 12 x 256 : w_w1^T
#define AW2_OFF 9216     // 12 x 256 : w_w2^T
#define H1T_OFF 12288    // 48 x 512 : h_w1^T K=32, idx (t*16+mt*8+ks)
#define H2T_OFF 36864    // 12 x 256 : h_w2^T K=16, idx (t*4+mt*2+ks)
#define BIAS_OFF 39936   // 576 bf16 : [L][t][32], L: u_b1,u_b2,w_b1,w_b2,h_b1,h_b2
#define G1_OFF 40512     // 176 x 512: g_w1 B-frags K=32, idx (nt*11+ks)
#define G2_OFF 130624    // 128 x 512: g_w2 B-frags K=32, idx (nt*8+ks)
// total 196160 shorts = 392320 B

typedef float f32x4 __attribute__((ext_vector_type(4)));
typedef short s16x4 __attribute__((ext_vector_type(4)));
typedef short s16x8 __attribute__((ext_vector_type(8)));

__device__ __forceinline__ short f2bf(float x) {
    unsigned u = __builtin_bit_cast(unsigned, x);
    u += 0x7fffu + ((u >> 16) & 1u);
    return (short)(u >> 16);
}
__device__ __forceinline__ float bf2f(short h) {
    unsigned u = ((unsigned)(unsigned short)h) << 16;
    return __builtin_bit_cast(float, u);
}
__device__ __forceinline__ float fast_tanh(float x) {
    float e = __builtin_amdgcn_exp2f(x * 2.8853900817779268f);
    return 1.f - 2.f * __builtin_amdgcn_rcpf(e + 1.f);
}
__device__ __forceinline__ s16x8 pack8(float4 a, float4 b) {
    s16x8 r = { f2bf(a.x), f2bf(a.y), f2bf(a.z), f2bf(a.w),
                f2bf(b.x), f2bf(b.y), f2bf(b.z), f2bf(b.w) };
    return r;
}
__device__ __forceinline__ f32x4 mfma32(s16x8 a, s16x8 b, f32x4 c) {
    return __builtin_amdgcn_mfma_f32_16x16x32_bf16(a, b, c, 0, 0, 0);
}
// 16x16x16 bf16: C/D layout == B layout -> chained layers need no lane shuffles.
// Use the builtin (compiler-visible scheduling/hazards); asm volatile fallback.
__device__ __forceinline__ f32x4 mfma16(s16x4 a, s16x4 b, f32x4 c) {
#if __has_builtin(__builtin_amdgcn_mfma_f32_16x16x16bf16_1k)
    return __builtin_amdgcn_mfma_f32_16x16x16bf16_1k(a, b, c, 0, 0, 0);
#else
    asm volatile("v_mfma_f32_16x16x16_bf16 %0, %1, %2, %0" : "+v"(c) : "v"(a), "v"(b));
    return c;
#endif
}

__global__ void prep_weights(const float* __restrict__ u_w1, const float* __restrict__ u_w2,
                             const float* __restrict__ w_w1, const float* __restrict__ w_w2,
                             const float* __restrict__ h_w1, const float* __restrict__ h_w2,
                             const float* __restrict__ u_b1, const float* __restrict__ u_b2,
                             const float* __restrict__ w_b1, const float* __restrict__ w_b2,
                             const float* __restrict__ h_b1, const float* __restrict__ h_b2,
                             const float* __restrict__ g_w1, const float* __restrict__ g_w2,
                             short* __restrict__ wsb)
{
    int tile = blockIdx.x, lane = threadIdx.x;
    int g = lane >> 4, q = lane & 15;
    if (tile < 6) {                         // Au1: K=32 A-frag of u_w1^T
        int t = tile >> 1, mt = tile & 1;
        const float* src = u_w1 + t * 1024;
        short* dst = wsb + AU1_OFF + tile * 512 + lane * 8;
        #pragma unroll
        for (int i = 0; i < 8; ++i) dst[i] = f2bf(src[(8 * g + i) * 32 + mt * 16 + q]);
    } else if (tile < 42) {                 // Au2/Aw1/Aw2: K=16 A-frags
        int m = (tile - 6) / 12, idx = (tile - 6) % 12;
        int mt = (idx >> 1) & 1, ks = idx & 1, t = idx >> 2;
        const float* mp = (m == 0) ? u_w2 : (m == 1) ? w_w1 : w_w2;
        const float* src = mp + t * 1024;
        short* dst = wsb + AU2_OFF + m * 3072 + idx * 256 + lane * 4;
        #pragma unroll
        for (int i = 0; i < 4; ++i) dst[i] = f2bf(src[(ks * 16 + 4 * g + i) * 32 + mt * 16 + q]);
    } else if (tile < 90) {                 // h1T: K=32 A-frags
        int idx = tile - 42;
        int t = idx >> 4, r = idx & 15, mt = r >> 3, ks = r & 7;
        const float* src = h_w1 + t * 8192;
        short* dst = wsb + H1T_OFF + idx * 512 + lane * 8;
        #pragma unroll
        for (int i = 0; i < 8; ++i) dst[i] = f2bf(src[(ks * 32 + 8 * g + i) * 32 + mt * 16 + q]);
    } else if (tile < 102) {                // h2T: K=16 A-frags
        int idx = tile - 90;
        int t = idx >> 2, mt = (idx >> 1) & 1, ks = idx & 1;
        const float* src = h_w2 + t * 1024;
        short* dst = wsb + H2T_OFF + idx * 256 + lane * 4;
        #pragma unroll
        for (int i = 0; i < 4; ++i) dst[i] = f2bf(src[(ks * 16 + 4 * g + i) * 32 + mt * 16 + q]);
    } else if (tile == 102) {               // biases -> bf16 [L][t][32]
        const float* bsrc[6] = {u_b1, u_b2, w_b1, w_b2, h_b1, h_b2};
        for (int j = lane; j < 576; j += 64)
            wsb[BIAS_OFF + j] = f2bf(bsrc[j / 96][j % 96]);
    } else if (tile < 279) {                // G1 B-frags
        int idx = tile - 103, nt = idx / 11, ks = idx % 11;
        short* dst = wsb + G1_OFF + idx * 512 + lane * 8;
        #pragma unroll
        for (int i = 0; i < 8; ++i)
            dst[i] = f2bf(g_w1[(size_t)(ks * 32 + 8 * g + i) * 256 + nt * 16 + q]);
    } else {                                // G2 B-frags
        int idx = tile - 279;
        short* dst = wsb + G2_OFF + idx * 512 + lane * 8;
        int nt = idx >> 3, ks = idx & 7;
        #pragma unroll
        for (int i = 0; i < 8; ++i)
            dst[i] = f2bf(g_w2[(size_t)(ks * 32 + 8 * g + i) * 256 + nt * 16 + q]);
    }
}

// LDS: f bf16 [32][356] = 22784 ; z f32 [32][97] = 12416 ; hx bf16 [72][36] = 5184
// phase E: H bf16 [32][260] = 16640 overlays z+hx. Total 40384 B -> 4 blocks/CU.
__launch_bounds__(256, 4)
__global__ void gnn_kernel(
    const float* __restrict__ elec, const float* __restrict__ nuc,
    const float* __restrict__ fs,  const float* __restrict__ fa,  const float* __restrict__ fn,
    const float* __restrict__ g_b1, const float* __restrict__ g_b2,
    const int* __restrict__ ss, const int* __restrict__ rs,
    const int* __restrict__ sa, const int* __restrict__ ra,
    const int* __restrict__ sn, const int* __restrict__ rn,
    const short* __restrict__ wsb,
    float* __restrict__ out)
{
    __shared__ __align__(16) char smem[40384];
    short* f_s  = (short*)smem;                  // [32][356]
    float* z_s  = (float*)(smem + 22784);        // [32][97]
    short* hx_s = (short*)(smem + 35200);        // [72][36]
    short* H_s  = (short*)(smem + 22784);        // [32][260] (phase E overlay)

    const int tid  = threadIdx.x;
    const int b    = blockIdx.x;
    const int lane = tid & 63, wv = tid >> 6;
    const int g    = lane >> 4, q = lane & 15;

    // ---------- Phase A: hx^T = h_w2^T @ tanh(h_w1^T @ X^T + b1) + b2 ----------
    if (wv > 0)
        for (int i = tid - 64; i < 32 * 97; i += 192) z_s[i] = 0.f;

    #pragma unroll 1
    for (int task = wv; task < 5; task += 4) {
        int t, nt;
        if (task < 4) { t = task >> 1; nt = task & 1; }
        else          { t = 2; nt = 0; }
        const float* rowp = (t < 2) ? elec + ((size_t)b * NE + nt * 16 + q) * EMB
                                    : nuc  + ((size_t)b * NN + (q < 8 ? q : 7)) * EMB;
        f32x4 c0 = {0.f, 0.f, 0.f, 0.f}, c1 = {0.f, 0.f, 0.f, 0.f};
        const short* wA = wsb + H1T_OFF + t * 16 * 512;
        #pragma unroll
        for (int ks = 0; ks < 8; ++ks) {
            float4 v0 = *(const float4*)(rowp + 32 * ks + 8 * g);
            float4 v1 = *(const float4*)(rowp + 32 * ks + 8 * g + 4);
            s16x8 Bf = pack8(v0, v1);
            if (t == 0) {   // stash elec bf16 into f cols 0..255
                int off = (nt * 16 + q) * 356 + 32 * ks + 8 * g;
                *(s16x4*)(f_s + off)     = __builtin_shufflevector(Bf, Bf, 0, 1, 2, 3);
                *(s16x4*)(f_s + off + 4) = __builtin_shufflevector(Bf, Bf, 4, 5, 6, 7);
            }
            s16x8 a0 = *(const s16x8*)(wA + ks * 512 + lane * 8);
            s16x8 a1 = *(const s16x8*)(wA + (8 + ks) * 512 + lane * 8);
            c0 = mfma32(a0, Bf, c0);
            c1 = mfma32(a1, Bf, c1);
        }
        s16x4 b1l = *(const s16x4*)(wsb + BIAS_OFF + (12 + t) * 32 + 4 * g);
        s16x4 b1h = *(const s16x4*)(wsb + BIAS_OFF + (12 + t) * 32 + 16 + 4 * g);
        s16x4 p0, p1;
        #pragma unroll
        for (int r = 0; r < 4; ++r) {
            p0[r] = f2bf(fast_tanh(c0[r] + bf2f(b1l[r])));
            p1[r] = f2bf(fast_tanh(c1[r] + bf2f(b1h[r])));
        }
        const short* wA2 = wsb + H2T_OFF + t * 4 * 256;
        f32x4 d0 = {0.f, 0.f, 0.f, 0.f}, d1 = {0.f, 0.f, 0.f, 0.f};
        d0 = mfma16(*(const s16x4*)(wA2 + 0 * 256 + lane * 4), p0, d0);
        d0 = mfma16(*(const s16x4*)(wA2 + 1 * 256 + lane * 4), p1, d0);
        d1 = mfma16(*(const s16x4*)(wA2 + 2 * 256 + lane * 4), p0, d1);
        d1 = mfma16(*(const s16x4*)(wA2 + 3 * 256 + lane * 4), p1, d1);
        if (t < 2 || q < 8) {
            s16x4 b2l = *(const s16x4*)(wsb + BIAS_OFF + (15 + t) * 32 + 4 * g);
            s16x4 b2h = *(const s16x4*)(wsb + BIAS_OFF + (15 + t) * 32 + 16 + 4 * g);
            s16x4 w0, w1;
            #pragma unroll
            for (int r = 0; r < 4; ++r) {
                w0[r] = f2bf(d0[r] + bf2f(b2l[r]));
                w1[r] = f2bf(d1[r] + bf2f(b2h[r]));
            }
            int row = t * 32 + nt * 16 + q;
            *(s16x4*)(hx_s + row * 36 + 4 * g)      = w0;
            *(s16x4*)(hx_s + row * 36 + 16 + 4 * g) = w1;
        }
    }
    __syncthreads();

    // ---------- Phase C: edge MLPs, fully register-chained ----------
    #pragma unroll 1
    for (int t = 0; t < 3; ++t) {
        const float* ft; const int* snd; const int* rcv; int cnt, zc0;
        if (t == 0)      { ft = fs; snd = ss; rcv = rs; cnt = E_SAME; zc0 = 32; }
        else if (t == 1) { ft = fa; snd = sa; rcv = ra; cnt = E_ANTI; zc0 = 64; }
        else             { ft = fn; snd = sn; rcv = rn; cnt = E_NE;   zc0 = 0;  }
        s16x8 Au1_0 = *(const s16x8*)(wsb + AU1_OFF + (t * 2 + 0) * 512 + lane * 8);
        s16x8 Au1_1 = *(const s16x8*)(wsb + AU1_OFF + (t * 2 + 1) * 512 + lane * 8);
        s16x4 Au2_[4], Aw1_[4], Aw2_[4];
        #pragma unroll
        for (int i = 0; i < 4; ++i) {
            Au2_[i] = *(const s16x4*)(wsb + AU2_OFF + (t * 4 + i) * 256 + lane * 4);
            Aw1_[i] = *(const s16x4*)(wsb + AW1_OFF + (t * 4 + i) * 256 + lane * 4);
            Aw2_[i] = *(const s16x4*)(wsb + AW2_OFF + (t * 4 + i) * 256 + lane * 4);
        }
        s16x4 bb1l = *(const s16x4*)(wsb + BIAS_OFF + (0 + t) * 32 + 4 * g);
        s16x4 bb1h = *(const s16x4*)(wsb + BIAS_OFF + (0 + t) * 32 + 16 + 4 * g);
        s16x4 bb2l = *(const s16x4*)(wsb + BIAS_OFF + (3 + t) * 32 + 4 * g);
        s16x4 bb2h = *(const s16x4*)(wsb + BIAS_OFF + (3 + t) * 32 + 16 + 4 * g);
        s16x4 bb3l = *(const s16x4*)(wsb + BIAS_OFF + (6 + t) * 32 + 4 * g);
        s16x4 bb3h = *(const s16x4*)(wsb + BIAS_OFF + (6 + t) * 32 + 16 + 4 * g);
        s16x4 bb4l = *(const s16x4*)(wsb + BIAS_OFF + (9 + t) * 32 + 4 * g);
        s16x4 bb4h = *(const s16x4*)(wsb + BIAS_OFF + (9 + t) * 32 + 16 + 4 * g);
        const short* hxt = hx_s + t * 32 * 36;
        int ntile = cnt >> 4;

        // prologue loads for first tile
        const float* fp = ft + ((size_t)b * cnt + wv * 16 + q) * TPS;
        float4 v0 = *(const float4*)(fp + 8 * g);
        float4 v1 = *(const float4*)(fp + 8 * g + 4);
        float4 rl = *(const float4*)(fp + 4 * g);
        float4 rh = *(const float4*)(fp + 16 + 4 * g);
        int se = snd[wv * 16 + q], re = rcv[wv * 16 + q];

        #pragma unroll 1
        for (int tt = wv; tt < ntile; tt += 4) {
            int tn = tt + 4;
            float4 n0 = {0,0,0,0}, n1 = {0,0,0,0}, nrl = {0,0,0,0}, nrh = {0,0,0,0};
            int ns = 0, nr = 0;
            if (tn < ntile) {   // prefetch next tile
                const float* np = ft + ((size_t)b * cnt + tn * 16 + q) * TPS;
                n0 = *(const float4*)(np + 8 * g);
                n1 = *(const float4*)(np + 8 * g + 4);
                nrl = *(const float4*)(np + 4 * g);
                nrh = *(const float4*)(np + 16 + 4 * g);
                ns = snd[tn * 16 + q]; nr = rcv[tn * 16 + q];
            }
            s16x8 B32 = pack8(v0, v1);
            // u layer1 (K=32)
            f32x4 c0 = {0.f,0.f,0.f,0.f}, c1 = {0.f,0.f,0.f,0.f};
            c0 = mfma32(Au1_0, B32, c0);
            c1 = mfma32(Au1_1, B32, c1);
            s16x4 p0, p1;
            #pragma unroll
            for (int r = 0; r < 4; ++r) {
                p0[r] = f2bf(fast_tanh(c0[r] + bf2f(bb1l[r])));
                p1[r] = f2bf(fast_tanh(c1[r] + bf2f(bb1h[r])));
            }
            // u layer2 (K=16 x2) + residual (f32 feats)
            f32x4 d0 = {0.f,0.f,0.f,0.f}, d1 = {0.f,0.f,0.f,0.f};
            d0 = mfma16(Au2_[0], p0, d0); d0 = mfma16(Au2_[1], p1, d0);
            d1 = mfma16(Au2_[2], p0, d1); d1 = mfma16(Au2_[3], p1, d1);
            const float* rlp = (const float*)&rl; const float* rhp = (const float*)&rh;
            #pragma unroll
            for (int r = 0; r < 4; ++r) {
                p0[r] = f2bf(rlp[r] + d0[r] + bf2f(bb2l[r]));
                p1[r] = f2bf(rhp[r] + d1[r] + bf2f(bb2h[r]));
            }
            // w layer1
            d0 = (f32x4){0.f,0.f,0.f,0.f}; d1 = (f32x4){0.f,0.f,0.f,0.f};
            d0 = mfma16(Aw1_[0], p0, d0); d0 = mfma16(Aw1_[1], p1, d0);
            d1 = mfma16(Aw1_[2], p0, d1); d1 = mfma16(Aw1_[3], p1, d1);
            #pragma unroll
            for (int r = 0; r < 4; ++r) {
                p0[r] = f2bf(fast_tanh(d0[r] + bf2f(bb3l[r])));
                p1[r] = f2bf(fast_tanh(d1[r] + bf2f(bb3h[r])));
            }
            // w layer2 -> we
            d0 = (f32x4){0.f,0.f,0.f,0.f}; d1 = (f32x4){0.f,0.f,0.f,0.f};
            d0 = mfma16(Aw2_[0], p0, d0); d0 = mfma16(Aw2_[1], p1, d0);
            d1 = mfma16(Aw2_[2], p0, d1); d1 = mfma16(Aw2_[3], p1, d1);
            // msg = we * hx[sender] ; scatter into z[receiver]
            s16x4 hlo = *(const s16x4*)(hxt + se * 36 + 4 * g);
            s16x4 hhi = *(const s16x4*)(hxt + se * 36 + 16 + 4 * g);
            float* zr = z_s + re * 97 + zc0 + 4 * g;
            #pragma unroll
            for (int r = 0; r < 4; ++r) {
                atomicAdd(zr + r,      (d0[r] + bf2f(bb4l[r])) * bf2f(hlo[r]));
                atomicAdd(zr + 16 + r, (d1[r] + bf2f(bb4h[r])) * bf2f(hhi[r]));
            }
            v0 = n0; v1 = n1; rl = nrl; rh = nrh; se = ns; re = nr;
        }
    }
    __syncthreads();

    // ---------- Phase D: f[:,256:352] = z * scale (bf16) ----------
    for (int i = tid; i < 32 * 96; i += 256) {
        int r = i / 96, c = i - r * 96;
        float sc = (c < 32) ? 0.125f : ((c < 64) ? (1.f / 15.f) : (1.f / 16.f));
        f_s[r * 356 + 256 + c] = f2bf(z_s[r * 97 + c] * sc);
    }
    __syncthreads();

    // ---------- Phase E layer1: H = tanh(f @ g_w1 + g_b1) ----------
    #pragma unroll 1
    for (int task = wv; task < 32; task += 4) {
        int mt = task >> 4, nt = task & 15;
        f32x4 acc = {0.f, 0.f, 0.f, 0.f};
        const short* ar = f_s + (mt * 16 + q) * 356 + 8 * g;
        const short* wp = wsb + G1_OFF + nt * 11 * 512 + lane * 8;
        #pragma unroll
        for (int ks = 0; ks < 11; ++ks) {
            s16x4 alo = *(const s16x4*)(ar + 32 * ks);
            s16x4 ahi = *(const s16x4*)(ar + 32 * ks + 4);
            s16x8 a = __builtin_shufflevector(alo, ahi, 0, 1, 2, 3, 4, 5, 6, 7);
            s16x8 bw = *(const s16x8*)(wp + ks * 512);
            acc = mfma32(a, bw, acc);
        }
        float bias = g_b1[nt * 16 + q];
        #pragma unroll
        for (int r = 0; r < 4; ++r)
            H_s[(mt * 16 + 4 * g + r) * 260 + nt * 16 + q] = f2bf(fast_tanh(acc[r] + bias));
    }
    __syncthreads();

    // ---------- Phase E layer2: out = elec + H @ g_w2 + g_b2 ----------
    #pragma unroll 1
    for (int task = wv; task < 32; task += 4) {
        int mt = task >> 4, nt = task & 15;
        f32x4 acc = {0.f, 0.f, 0.f, 0.f};
        const short* ar = H_s + (mt * 16 + q) * 260 + 8 * g;
        const short* wp = wsb + G2_OFF + nt * 8 * 512 + lane * 8;
        #pragma unroll
        for (int ks = 0; ks < 8; ++ks) {
            s16x4 alo = *(const s16x4*)(ar + 32 * ks);
            s16x4 ahi = *(const s16x4*)(ar + 32 * ks + 4);
            s16x8 a = __builtin_shufflevector(alo, ahi, 0, 1, 2, 3, 4, 5, 6, 7);
            s16x8 bw = *(const s16x8*)(wp + ks * 512);
            acc = mfma32(a, bw, acc);
        }
        float bias = g_b2[nt * 16 + q];
        #pragma unroll
        for (int r = 0; r < 4; ++r) {
            int row = mt * 16 + 4 * g + r, col = nt * 16 + q;
            size_t o = ((size_t)b * NE + row) * EMB + col;
            out[o] = bf2f(f_s[row * 356 + col]) + acc[r] + bias;
        }
    }
}

extern "C" void kernel_launch(void* const* d_in, const int* in_sizes, int n_in,
                              void* d_out, int out_size, void* d_ws, size_t ws_size,
                              hipStream_t stream) {
    const float* elec = (const float*)d_in[0];
    const float* nuc  = (const float*)d_in[1];
    const float* fs   = (const float*)d_in[2];
    const float* fa   = (const float*)d_in[3];
    const float* fn   = (const float*)d_in[4];
    const float* u_w1 = (const float*)d_in[5];
    const float* u_b1 = (const float*)d_in[6];
    const float* u_w2 = (const float*)d_in[7];
    const float* u_b2 = (const float*)d_in[8];
    const float* w_w1 = (const float*)d_in[9];
    const float* w_b1 = (const float*)d_in[10];
    const float* w_w2 = (const float*)d_in[11];
    const float* w_b2 = (const float*)d_in[12];
    const float* h_w1 = (const float*)d_in[13];
    const float* h_b1 = (const float*)d_in[14];
    const float* h_w2 = (const float*)d_in[15];
    const float* h_b2 = (const float*)d_in[16];
    const float* g_w1 = (const float*)d_in[17];
    const float* g_b1 = (const float*)d_in[18];
    const float* g_w2 = (const float*)d_in[19];
    const float* g_b2 = (const float*)d_in[20];
    const int* ss = (const int*)d_in[21];
    const int* rs = (const int*)d_in[22];
    const int* sa = (const int*)d_in[23];
    const int* ra = (const int*)d_in[24];
    const int* sn = (const int*)d_in[25];
    const int* rn = (const int*)d_in[26];

    short* wsb = (short*)d_ws;
    int nb = in_sizes[0] / (NE * EMB);

    prep_weights<<<407, 64, 0, stream>>>(u_w1, u_w2, w_w1, w_w2, h_w1, h_w2,
                                         u_b1, u_b2, w_b1, w_b2, h_b1, h_b2,
                                         g_w1, g_w2, wsb);
    gnn_kernel<<<nb, 256, 0, stream>>>(elec, nuc, fs, fa, fn, g_b1, g_b2,
                                       ss, rs, sa, ra, sn, rn, wsb, (float*)d_out);
}